// Round 9
// baseline (927.527 us; speedup 1.0000x reference)
//
#include <hip/hip_runtime.h>

typedef __attribute__((ext_vector_type(8))) short bf16x8;
typedef __attribute__((ext_vector_type(4))) float f32x4;
typedef unsigned short u16;
typedef unsigned int u32;
typedef unsigned long long u64;

#define DEV static __device__ __forceinline__
DEV u16 f2bf(float f) { u32 i = __float_as_uint(f); i += 0x7fffu + ((i >> 16) & 1u); return (u16)(i >> 16); }
DEV float bf2f(u16 u) { return __uint_as_float(((u32)u) << 16); }

constexpr int Mn = 8192;
constexpr int Pn = 256;
constexpr int Kn = 32;
constexpr float R2 = 0.09f;

// =====================================================================
// k_voting_off v4 — round-8 verbatim (proven).
// =====================================================================
__global__ __launch_bounds__(256, 2) void k_voting_off(
    const float* __restrict__ sxyz,   // (65536,2)
    const float* __restrict__ sfeat,  // (65536,256)
    const float* __restrict__ ow1, const float* __restrict__ ob1,
    const float* __restrict__ os1, const float* __restrict__ ot1,
    const float* __restrict__ ow2, const float* __restrict__ ob2,
    float* __restrict__ votes)        // (65536,2)
{
  __shared__ __align__(16) char vsm[68608];
  float (*Xc)[68]  = (float(*)[68])vsm;             // 16x68x4  = 4352
  float (*Wc)[260] = (float(*)[260])(vsm + 4352);   // 16x260x4 = 16640
  float (*Hst)[67] = (float(*)[67])vsm;             // 256x67x4 = 68608 (union)

  const int tid = threadIdx.x;
  const int row0 = blockIdx.x * 64;
  const int wv = tid >> 6, lane = tid & 63;
  const int rr = wv * 16 + (lane >> 5) * 8;   // thread's first row (mult of 8)
  const int c4 = (lane & 31) * 4;             // first col of low group

  float acc[8][8];
#pragma unroll
  for (int r = 0; r < 8; ++r)
#pragma unroll
    for (int j = 0; j < 8; ++j) acc[r][j] = 0.f;

  for (int kc = 0; kc < 16; ++kc) {
    __syncthreads();
    // stage W chunk: Wc[k][o] = ow1[o*256 + kc*16 + k]
    for (int i = tid; i < 256 * 16; i += 256) {
      int o = i >> 4, k = i & 15;
      Wc[k][o] = ow1[o * 256 + kc * 16 + k];
    }
    // stage X chunk: Xc[k][r] = sfeat[(row0+r)*256 + kc*16 + k]
    for (int i = tid; i < 64 * 16; i += 256) {
      int r = i >> 4, k = i & 15;
      Xc[k][r] = sfeat[(row0 + r) * 256 + kc * 16 + k];
    }
    __syncthreads();
#pragma unroll
    for (int k = 0; k < 16; ++k) {
      float4 x0 = *(const float4*)&Xc[k][rr];        // rows rr..rr+3 (broadcast)
      float4 x1 = *(const float4*)&Xc[k][rr + 4];    // rows rr+4..rr+7
      float4 w0 = *(const float4*)&Wc[k][c4];        // cols c4..c4+3
      float4 w1 = *(const float4*)&Wc[k][128 + c4];  // cols 128+c4..+3
      float x[8] = {x0.x, x0.y, x0.z, x0.w, x1.x, x1.y, x1.z, x1.w};
      float w[8] = {w0.x, w0.y, w0.z, w0.w, w1.x, w1.y, w1.z, w1.w};
#pragma unroll
      for (int r = 0; r < 8; ++r)
#pragma unroll
        for (int j = 0; j < 8; ++j)
          acc[r][j] = fmaf(x[r], w[j], acc[r][j]);
    }
  }
  __syncthreads();   // Xc/Wc dead; reuse union as Hst
#pragma unroll
  for (int j = 0; j < 8; ++j) {
    int o = (j < 4) ? (c4 + j) : (124 + c4 + j);  // j>=4: 128 + c4 + (j-4)
    float bb = ob1[o], ss = os1[o], tt = ot1[o];
#pragma unroll
    for (int r = 0; r < 8; ++r)
      Hst[o][rr + r] = fmaxf((acc[r][j] + bb) * ss + tt, 0.f);
  }
  __syncthreads();

  if (tid < 128) {
    int r = tid >> 1, o = tid & 1;
    float a = 0.f;
    for (int k = 0; k < 256; ++k)
      a = fmaf(Hst[k][r], ow2[o * 256 + k], a);
    a += ob2[o];
    int row = row0 + r;
    votes[row * 2 + o] = sxyz[row * 2 + o] + a;
  }
}

// =====================================================================
// k_fps_vf — fused fps+vf (round-7 proven structure).
//   fps scan now ds_read_b128: thread t scans point pairs
//   {s*1024+2t, s*1024+2t+1}, 8 x b128 instead of 16 x b64 (half the
//   LDS issue slots, same bytes, 16B-aligned, conflict-free). The
//   partition change is legal: total order (dist desc, idx asc) is
//   partition-invariant; within-thread scan stays ascending-index with
//   strict '>' => selections bit-identical.
// =====================================================================
__global__ __launch_bounds__(512) void k_fps_vf(
    const float* __restrict__ votes, float* __restrict__ nxyz,
    float* __restrict__ out,
    const float* __restrict__ sfeat, const u16* __restrict__ FW1h,
    const float* __restrict__ fb1, const float* __restrict__ fs1,
    const float* __restrict__ ft1, const u16* __restrict__ FW2b,
    const float* __restrict__ fb2, u16* __restrict__ vfeat)
{
  __shared__ __align__(16) char smem[86016];
  const int tid = threadIdx.x;

  if (blockIdx.x < 8) {
    // ================= FPS role =================
    const int b = blockIdx.x;
    const float* vb = votes + b * Mn * 2;
    float2* xy   = (float2*)smem;                  // 65536 B
    u32*   Sd    = (u32*)(smem + 65536);           // [2][32]
    u32*   Sl    = (u32*)(smem + 65536 + 256);     // [2][32]
    float* histx = (float*)(smem + 66048);
    float* histy = (float*)(smem + 67072);

    {
      const float4* vb4 = (const float4*)vb;
#pragma unroll
      for (int j = tid; j < Mn / 2; j += 512) {
        float4 v = vb4[j];
        *(float4*)&xy[2 * j] = v;
      }
    }
    float dist[16];
#pragma unroll
    for (int s = 0; s < 16; ++s) dist[s] = 1e10f;
    __syncthreads();

    float cx = xy[0].x, cy = xy[0].y;
    if (tid == 0) { histx[0] = cx; histy[0] = cy; }

    for (int it = 1; it < Pn; ++it) {
      float bd = -1.f; int bi = 0;
#pragma unroll
      for (int s = 0; s < 8; ++s) {
        int base = s * 1024 + 2 * tid;
        float4 p2 = *(const float4*)&xy[base];   // pts base, base+1
        float dx0 = p2.x - cx, dy0 = p2.y - cy;
        float d0 = fminf(dist[2 * s], dx0 * dx0 + dy0 * dy0);
        dist[2 * s] = d0;
        if (d0 > bd) { bd = d0; bi = base; }
        float dx1 = p2.z - cx, dy1 = p2.w - cy;
        float d1 = fminf(dist[2 * s + 1], dx1 * dx1 + dy1 * dy1);
        dist[2 * s + 1] = d1;
        if (d1 > bd) { bd = d1; bi = base + 1; }
      }

      u32 hd = __float_as_uint(bd), hl = ~(u32)bi;

#define FPS_ROR(VD, VL, N)                                                      \
      {                                                                         \
        u32 od = (u32)__builtin_amdgcn_update_dpp(0, (int)VD, 0x120 + N, 0xF, 0xF, false); \
        u32 ol = (u32)__builtin_amdgcn_update_dpp(0, (int)VL, 0x120 + N, 0xF, 0xF, false); \
        bool g = (od > VD) || (od == VD && ol > VL);                            \
        VD = g ? od : VD; VL = g ? ol : VL;                                     \
      }
      FPS_ROR(hd, hl, 8)
      FPS_ROR(hd, hl, 4)
      FPS_ROR(hd, hl, 2)
      FPS_ROR(hd, hl, 1)

      const int buf = it & 1;
      if ((tid & 15) == 0) {
        int row = tid >> 4;              // 0..31
        Sd[buf * 32 + row] = hd; Sl[buf * 32 + row] = hl;
      }
      __syncthreads();

      int rr = tid & 15;
      u32 rd = Sd[buf * 32 + rr], rl = Sl[buf * 32 + rr];
      {
        u32 od = Sd[buf * 32 + 16 + rr], ol = Sl[buf * 32 + 16 + rr];
        bool g = (od > rd) || (od == rd && ol > rl);
        rd = g ? od : rd; rl = g ? ol : rl;
      }
      FPS_ROR(rd, rl, 8)
      FPS_ROR(rd, rl, 4)
      FPS_ROR(rd, rl, 2)
      FPS_ROR(rd, rl, 1)
#undef FPS_ROR

      int widx = (int)(~rl);
      float2 w = xy[widx];               // uniform addr -> LDS broadcast
      cx = w.x; cy = w.y;
      if (tid == 0) { histx[it] = cx; histy[it] = cy; }
    }
    __syncthreads();
    if (tid < 256) {
      float2 o2; o2.x = histx[tid]; o2.y = histy[tid];
      *(float2*)&nxyz[(b * Pn + tid) * 2] = o2;
      *(float2*)&out[(b * Pn + tid) * 2] = o2;
    }
  } else {
    // ================= VF role (8-wave remap, proven) =================
    const int bx = blockIdx.x - 8;
    const int row0 = bx * 128;
    u16* Hs = (u16*)smem;                  // 128*136*2 = 34816
    u16* As = (u16*)(smem + 34816);        // 128*40*2  = 10240
    u16* Bs = (u16*)(smem + 45056);        // 128*40*2  = 10240

    const int wid = tid >> 6, lane = tid & 63, m16 = lane & 15, quad = lane >> 4;
    const int wr = wid >> 2;        // 0..1 : 64-row group
    const int wc4 = wid & 3;        // 0..3 : 32-col group
    const int sr = tid >> 2, sk = (tid & 3) * 8;

    f32x4 acc2[4][2];
#pragma unroll
    for (int mt = 0; mt < 4; ++mt)
#pragma unroll
      for (int nt = 0; nt < 2; ++nt) acc2[mt][nt] = (f32x4){0.f, 0.f, 0.f, 0.f};

    for (int h = 0; h < 2; ++h) {
      f32x4 acc[4][2];
#pragma unroll
      for (int mt = 0; mt < 4; ++mt)
#pragma unroll
        for (int nt = 0; nt < 2; ++nt) acc[mt][nt] = (f32x4){0.f, 0.f, 0.f, 0.f};

      for (int s = 0; s < 8; ++s) {
        __syncthreads();
        {
          const float* src = &sfeat[(row0 + sr) * 256 + s * 32 + sk];
          float4 v0 = *(const float4*)&src[0];
          float4 v1 = *(const float4*)&src[4];
          u32 packed[4];
          packed[0] = (u32)f2bf(v0.x) | ((u32)f2bf(v0.y) << 16);
          packed[1] = (u32)f2bf(v0.z) | ((u32)f2bf(v0.w) << 16);
          packed[2] = (u32)f2bf(v1.x) | ((u32)f2bf(v1.y) << 16);
          packed[3] = (u32)f2bf(v1.z) | ((u32)f2bf(v1.w) << 16);
          *(uint4*)&As[sr * 40 + sk] = *(uint4*)&packed[0];
          *(uint4*)&Bs[sr * 40 + sk] =
              *(const uint4*)&FW1h[(h * 128 + sr) * 256 + s * 32 + sk];
        }
        __syncthreads();
#pragma unroll
        for (int mt = 0; mt < 4; ++mt) {
          bf16x8 af = *(const bf16x8*)&As[(wr * 64 + mt * 16 + m16) * 40 + quad * 8];
#pragma unroll
          for (int nt = 0; nt < 2; ++nt) {
            bf16x8 bfr = *(const bf16x8*)&Bs[(wc4 * 32 + nt * 16 + m16) * 40 + quad * 8];
            acc[mt][nt] = __builtin_amdgcn_mfma_f32_16x16x32_bf16(af, bfr, acc[mt][nt], 0, 0, 0);
          }
        }
      }
      __syncthreads();
#pragma unroll
      for (int nt = 0; nt < 2; ++nt) {
        int colL = wc4 * 32 + nt * 16 + m16;
        int col = h * 128 + colL;
        float bb = fb1[col], ss = fs1[col], tt = ft1[col];
#pragma unroll
        for (int mt = 0; mt < 4; ++mt) {
          int rL = wr * 64 + mt * 16 + quad * 4;
#pragma unroll
          for (int r = 0; r < 4; ++r)
            Hs[(rL + r) * 136 + colL] = f2bf(fmaxf((acc[mt][nt][r] + bb) * ss + tt, 0.f));
        }
      }
      for (int s2 = 0; s2 < 4; ++s2) {
        __syncthreads();
        {
          *(uint4*)&Bs[sr * 40 + sk] =
              *(const uint4*)&FW2b[sr * 256 + h * 128 + s2 * 32 + sk];
        }
        __syncthreads();
#pragma unroll
        for (int mt = 0; mt < 4; ++mt) {
          bf16x8 af = *(const bf16x8*)&Hs[(wr * 64 + mt * 16 + m16) * 136 + s2 * 32 + quad * 8];
#pragma unroll
          for (int nt = 0; nt < 2; ++nt) {
            bf16x8 bfr = *(const bf16x8*)&Bs[(wc4 * 32 + nt * 16 + m16) * 40 + quad * 8];
            acc2[mt][nt] = __builtin_amdgcn_mfma_f32_16x16x32_bf16(af, bfr, acc2[mt][nt], 0, 0, 0);
          }
        }
      }
    }
#pragma unroll
    for (int nt = 0; nt < 2; ++nt) {
      int col = wc4 * 32 + nt * 16 + m16;
      float bb = fb2[col];
#pragma unroll
      for (int mt = 0; mt < 4; ++mt) {
        int rbase = row0 + wr * 64 + mt * 16 + quad * 4;
#pragma unroll
        for (int r = 0; r < 4; ++r)
          vfeat[(rbase + r) * 128 + col] = f2bf(acc2[mt][nt][r] + bb);
      }
    }
  }
}

// =====================================================================
// Prep: bf16 weight conversions. No deps -> launched first.
// =====================================================================
__global__ __launch_bounds__(256) void k_prep(
    const float* __restrict__ fw1, const float* __restrict__ fw2,
    const float* __restrict__ aw1, const float* __restrict__ aw2,
    u16* __restrict__ FW1h, u16* __restrict__ FW2b,
    u16* __restrict__ AW1b, u16* __restrict__ AW2b)
{
  const int gid = blockIdx.x * 256 + threadIdx.x;
  const int gsz = gridDim.x * 256;
  for (int i = gid; i < 65536; i += gsz) FW1h[i] = f2bf(fw1[i]);
  for (int i = gid; i < 32768; i += gsz) FW2b[i] = f2bf(fw2[i]);
  for (int i = gid; i < 65536; i += gsz) AW2b[i] = f2bf(aw2[i]);
  for (int i = gid; i < 49152; i += gsz) {
    int o = i / 192, k = i % 192;
    AW1b[i] = (k < 130) ? f2bf(aw1[o * 130 + k]) : (u16)0;
  }
}

// =====================================================================
// k_ballq_agg_head — ballq fused onto the front of agg_head.
//   agg block bp consumes exactly ballq block bp's 32 indices: compute
//   them here (ballq body verbatim, gidx -> LDS gix), drop the gidx
//   round-trip and one 2048-block kernel boundary. ballq's d2[32] regs
//   die before the MFMA phase (allocator reuses). VALU-ballq of some
//   blocks overlaps MFMA-agg of others (separate pipes).
//   Bit-exact: identical expressions and order throughout.
// =====================================================================
__global__ __launch_bounds__(256) void k_ballq_agg_head(
    const float* __restrict__ votes, const u16* __restrict__ vfeat,
    const float* __restrict__ nxyz,
    const u16* __restrict__ AW1b, const float* __restrict__ ab1,
    const float* __restrict__ as1, const float* __restrict__ at1,
    const u16* __restrict__ AW2b, const float* __restrict__ ab2,
    const float* __restrict__ as2, const float* __restrict__ at2,
    const float* __restrict__ pw1, const float* __restrict__ pb1,
    const float* __restrict__ ps1, const float* __restrict__ pt1,
    const float* __restrict__ pw2, const float* __restrict__ pb2,
    const float* __restrict__ ps2, const float* __restrict__ pt2,
    const float* __restrict__ objw, const float* __restrict__ objb,
    const float* __restrict__ clsw, const float* __restrict__ clsb,
    float* __restrict__ out)
{
  __shared__ u16 U[32 * 264];
  __shared__ u16 Bs[256 * 72];
  __shared__ int gix[32];
  __shared__ float gvx[32], gvy[32];
  __shared__ float sd[4];
  __shared__ int si[4];
  __shared__ int swi;
  u16* CombA = U;
  u16* As = U;
  float* x2T = (float*)Bs;
  float* xr = (float*)U;          // head buffers aliased on dead U
  float* y1 = ((float*)U) + 256;
  float* y2 = ((float*)U) + 512;

  const int bp = blockIdx.x, tid = threadIdx.x, b = bp >> 8;

  // ---------------- ballq phase (proven body; gidx -> LDS gix) ----------------
  {
    const float* vb = votes + b * Mn * 2;
    const float sx0 = nxyz[bp * 2], sy0 = nxyz[bp * 2 + 1];
    const float a = sx0 * sx0 + sy0 * sy0;
    float d2[32];
#pragma unroll
    for (int s = 0; s < 32; ++s) {
      int i = tid * 32 + s;
      float x = vb[i * 2], y = vb[i * 2 + 1];
      d2[s] = (a + (x * x + y * y)) - 2.f * (sx0 * x + sy0 * y);
    }
    unsigned mask = 0;
    for (int kk = 0; kk < Kn; ++kk) {
      float bd = 3.4e38f; int bi = 0x7fffffff;
#pragma unroll
      for (int s = 0; s < 32; ++s)
        if (!((mask >> s) & 1u) && d2[s] < bd) { bd = d2[s]; bi = tid * 32 + s; }
#pragma unroll
      for (int off = 32; off > 0; off >>= 1) {
        float od = __shfl_xor(bd, off);
        int oi = __shfl_xor(bi, off);
        if (od < bd || (od == bd && oi < bi)) { bd = od; bi = oi; }
      }
      if ((tid & 63) == 0) { sd[tid >> 6] = bd; si[tid >> 6] = bi; }
      __syncthreads();
      if (tid == 0) {
#pragma unroll
        for (int w = 1; w < 4; ++w)
          if (sd[w] < bd || (sd[w] == bd && si[w] < bi)) { bd = sd[w]; bi = si[w]; }
        swi = bi;
        gix[kk] = (bd > R2) ? 0 : bi;
      }
      __syncthreads();
      int wi = swi;
      if ((wi >> 5) == tid) mask |= 1u << (wi & 31);
    }
  }
  __syncthreads();

  // ---------------- agg phase (proven body; gix from LDS) ----------------
  if (tid < 32) {
    int g = gix[tid];
    gvx[tid] = votes[(b * Mn + g) * 2];
    gvy[tid] = votes[(b * Mn + g) * 2 + 1];
  }
  __syncthreads();
  const float sx = nxyz[bp * 2], sy = nxyz[bp * 2 + 1];

  if (tid < 192) {
    int row = tid / 6, c = tid % 6;
    const u16* vsrc = &vfeat[(b * Mn + gix[row]) * 128];
    u16* dst = &CombA[row * 200 + c * 32];
    if (c == 0) {
      dst[0] = f2bf(gvx[row] - sx);
      dst[1] = f2bf(gvy[row] - sy);
      for (int k = 2; k < 32; ++k) dst[k] = vsrc[k - 2];
    } else if (c <= 3) {
      for (int k = 0; k < 32; ++k) dst[k] = vsrc[c * 32 + k - 2];
    } else if (c == 4) {
      dst[0] = vsrc[126]; dst[1] = vsrc[127];
      for (int k = 2; k < 32; ++k) dst[k] = 0;
    } else {
      for (int k = 0; k < 32; ++k) dst[k] = 0;
    }
  }

  const int wid = tid >> 6, lane = tid & 63, m16 = lane & 15, quad = lane >> 4;
  const int mt = wid & 1, nh = wid >> 1;

  f32x4 acc[8];
#pragma unroll
  for (int nt = 0; nt < 8; ++nt) acc[nt] = (f32x4){0.f, 0.f, 0.f, 0.f};
  for (int s = 0; s < 3; ++s) {
    __syncthreads();
    for (int i = tid; i < 4096; i += 256) {
      int n = i >> 4, c4 = i & 15;
      *(uint2*)&Bs[n * 72 + c4 * 4] = *(const uint2*)&AW1b[n * 192 + s * 64 + c4 * 4];
    }
    __syncthreads();
#pragma unroll
    for (int ks = 0; ks < 2; ++ks) {
      bf16x8 af = *(const bf16x8*)&CombA[(mt * 16 + m16) * 200 + s * 64 + ks * 32 + quad * 8];
#pragma unroll
      for (int nt = 0; nt < 8; ++nt) {
        bf16x8 bf_ = *(const bf16x8*)&Bs[(nh * 128 + nt * 16 + m16) * 72 + ks * 32 + quad * 8];
        acc[nt] = __builtin_amdgcn_mfma_f32_16x16x32_bf16(af, bf_, acc[nt], 0, 0, 0);
      }
    }
  }
  __syncthreads();
#pragma unroll
  for (int nt = 0; nt < 8; ++nt) {
    int col = nh * 128 + nt * 16 + m16;
    float bb = ab1[col], ss = as1[col], tt = at1[col];
#pragma unroll
    for (int r = 0; r < 4; ++r) {
      int samp = mt * 16 + quad * 4 + r;
      As[samp * 264 + col] = f2bf(fmaxf((acc[nt][r] + bb) * ss + tt, 0.f));
    }
  }

  f32x4 acc2[8];
#pragma unroll
  for (int nt = 0; nt < 8; ++nt) acc2[nt] = (f32x4){0.f, 0.f, 0.f, 0.f};
  for (int s = 0; s < 4; ++s) {
    __syncthreads();
    for (int i = tid; i < 4096; i += 256) {
      int n = i >> 4, c4 = i & 15;
      *(uint2*)&Bs[n * 72 + c4 * 4] = *(const uint2*)&AW2b[n * 256 + s * 64 + c4 * 4];
    }
    __syncthreads();
#pragma unroll
    for (int ks = 0; ks < 2; ++ks) {
      bf16x8 af = *(const bf16x8*)&As[(mt * 16 + m16) * 264 + s * 64 + ks * 32 + quad * 8];
#pragma unroll
      for (int nt = 0; nt < 8; ++nt) {
        bf16x8 bf_ = *(const bf16x8*)&Bs[(nh * 128 + nt * 16 + m16) * 72 + ks * 32 + quad * 8];
        acc2[nt] = __builtin_amdgcn_mfma_f32_16x16x32_bf16(af, bf_, acc2[nt], 0, 0, 0);
      }
    }
  }
  __syncthreads();
#pragma unroll
  for (int nt = 0; nt < 8; ++nt) {
    int col = nh * 128 + nt * 16 + m16;
    float bb = ab2[col], ss = as2[col], tt = at2[col];
#pragma unroll
    for (int r = 0; r < 4; ++r) {
      int samp = mt * 16 + quad * 4 + r;
      x2T[col * 33 + samp] = fmaxf((acc2[nt][r] + bb) * ss + tt, 0.f);
    }
  }
  __syncthreads();     // As (U) reads done before this; U now dead
  {
    float m = x2T[tid * 33];
#pragma unroll
    for (int s2 = 1; s2 < 32; ++s2) m = fmaxf(m, x2T[tid * 33 + s2]);
    xr[tid] = m;       // == pooled[bp*256+tid], bit-exact
  }
  __syncthreads();

  // ---- head (identical arithmetic to proven k_head) ----
  {
    float a = 0.f;
    for (int c = 0; c < 256; ++c) a = fmaf(xr[c], pw1[tid * 256 + c], a);
    a = (a + pb1[tid]) * ps1[tid] + pt1[tid];
    y1[tid] = fmaxf(a, 0.f);
  }
  __syncthreads();
  if (tid < 128) {
    float a = 0.f;
    for (int c = 0; c < 256; ++c) a = fmaf(y1[c], pw2[tid * 256 + c], a);
    a = (a + pb2[tid]) * ps2[tid] + pt2[tid];
    y2[tid] = fmaxf(a, 0.f);
  }
  __syncthreads();
  if (tid < 10) {
    float a = 0.f;
    for (int c = 0; c < 128; ++c) a = fmaf(y2[c], clsw[tid * 128 + c], a);
    out[6144 + bp * 10 + tid] = a + clsb[tid];
  } else if (tid == 10) {
    float a = 0.f;
    for (int c = 0; c < 128; ++c) a = fmaf(y2[c], objw[c], a);
    out[4096 + bp] = a + objb[0];
  }
}

// =====================================================================
extern "C" void kernel_launch(void* const* d_in, const int* in_sizes, int n_in,
                              void* d_out, int out_size, void* d_ws, size_t ws_size,
                              hipStream_t stream)
{
  (void)in_sizes; (void)n_in; (void)out_size; (void)ws_size;
  const float* sxyz  = (const float*)d_in[0];
  const float* sfeat = (const float*)d_in[1];
  const float* ow1 = (const float*)d_in[2];
  const float* ob1 = (const float*)d_in[3];
  const float* os1 = (const float*)d_in[4];
  const float* ot1 = (const float*)d_in[5];
  const float* ow2 = (const float*)d_in[6];
  const float* ob2 = (const float*)d_in[7];
  const float* fw1 = (const float*)d_in[8];
  const float* fb1 = (const float*)d_in[9];
  const float* fs1 = (const float*)d_in[10];
  const float* ft1 = (const float*)d_in[11];
  const float* fw2 = (const float*)d_in[12];
  const float* fb2 = (const float*)d_in[13];
  const float* aw1 = (const float*)d_in[14];
  const float* ab1 = (const float*)d_in[15];
  const float* as1 = (const float*)d_in[16];
  const float* at1 = (const float*)d_in[17];
  const float* aw2 = (const float*)d_in[18];
  const float* ab2 = (const float*)d_in[19];
  const float* as2 = (const float*)d_in[20];
  const float* at2 = (const float*)d_in[21];
  const float* pw1 = (const float*)d_in[22];
  const float* pb1 = (const float*)d_in[23];
  const float* ps1 = (const float*)d_in[24];
  const float* pt1 = (const float*)d_in[25];
  const float* pw2 = (const float*)d_in[26];
  const float* pb2 = (const float*)d_in[27];
  const float* ps2 = (const float*)d_in[28];
  const float* pt2 = (const float*)d_in[29];
  const float* objw = (const float*)d_in[30];
  const float* objb = (const float*)d_in[31];
  const float* clsw = (const float*)d_in[32];
  const float* clsb = (const float*)d_in[33];

  char* ws = (char*)d_ws;
  float* votes  = (float*)(ws + 0);             //    524,288
  u16*   vfeat  = (u16*)  (ws + 524288);        // 16,777,216
  float* nxyz   = (float*)(ws + 17301504);      //     16,384
  u16*   FW1h   = (u16*)  (ws + 19677184);      //    131,072
  u16*   FW2b   = (u16*)  (ws + 19808256);      //     65,536
  u16*   AW1b   = (u16*)  (ws + 19873792);      //     98,304
  u16*   AW2b   = (u16*)  (ws + 19972096);      //    131,072
  float* out    = (float*)d_out;

  // prep first (no deps) so vf-role blocks of the fused kernel are ready
  k_prep<<<dim3(256), dim3(256), 0, stream>>>(
      fw1, fw2, aw1, aw2, FW1h, FW2b, AW1b, AW2b);

  k_voting_off<<<dim3(1024), dim3(256), 0, stream>>>(
      sxyz, sfeat, ow1, ob1, os1, ot1, ow2, ob2, votes);

  // fused: blocks 0..7 = FPS (one per batch), blocks 8..519 = VF
  k_fps_vf<<<dim3(520), dim3(512), 0, stream>>>(
      votes, nxyz, out,
      sfeat, FW1h, fb1, fs1, ft1, FW2b, fb2, vfeat);

  // fused: ballq + aggregation + proposal head
  k_ballq_agg_head<<<dim3(2048), dim3(256), 0, stream>>>(
      votes, vfeat, nxyz, AW1b, ab1, as1, at1,
      AW2b, ab2, as2, at2,
      pw1, pb1, ps1, pt1, pw2, pb2, ps2, pt2,
      objw, objb, clsw, clsb, out);
}

// Round 10
// 854.938 us; speedup vs baseline: 1.0849x; 1.0849x over previous
//
#include <hip/hip_runtime.h>

typedef __attribute__((ext_vector_type(8))) short bf16x8;
typedef __attribute__((ext_vector_type(4))) float f32x4;
typedef unsigned short u16;
typedef unsigned int u32;
typedef unsigned long long u64;

#define DEV static __device__ __forceinline__
DEV u16 f2bf(float f) { u32 i = __float_as_uint(f); i += 0x7fffu + ((i >> 16) & 1u); return (u16)(i >> 16); }
DEV float bf2f(u16 u) { return __uint_as_float(((u32)u) << 16); }

constexpr int Mn = 8192;
constexpr int Pn = 256;
constexpr int Kn = 32;
constexpr float R2 = 0.09f;

// =====================================================================
// k_voting_off v4 — round-8 verbatim (proven).
// =====================================================================
__global__ __launch_bounds__(256, 2) void k_voting_off(
    const float* __restrict__ sxyz,   // (65536,2)
    const float* __restrict__ sfeat,  // (65536,256)
    const float* __restrict__ ow1, const float* __restrict__ ob1,
    const float* __restrict__ os1, const float* __restrict__ ot1,
    const float* __restrict__ ow2, const float* __restrict__ ob2,
    float* __restrict__ votes)        // (65536,2)
{
  __shared__ __align__(16) char vsm[68608];
  float (*Xc)[68]  = (float(*)[68])vsm;             // 16x68x4  = 4352
  float (*Wc)[260] = (float(*)[260])(vsm + 4352);   // 16x260x4 = 16640
  float (*Hst)[67] = (float(*)[67])vsm;             // 256x67x4 = 68608 (union)

  const int tid = threadIdx.x;
  const int row0 = blockIdx.x * 64;
  const int wv = tid >> 6, lane = tid & 63;
  const int rr = wv * 16 + (lane >> 5) * 8;   // thread's first row (mult of 8)
  const int c4 = (lane & 31) * 4;             // first col of low group

  float acc[8][8];
#pragma unroll
  for (int r = 0; r < 8; ++r)
#pragma unroll
    for (int j = 0; j < 8; ++j) acc[r][j] = 0.f;

  for (int kc = 0; kc < 16; ++kc) {
    __syncthreads();
    // stage W chunk: Wc[k][o] = ow1[o*256 + kc*16 + k]
    for (int i = tid; i < 256 * 16; i += 256) {
      int o = i >> 4, k = i & 15;
      Wc[k][o] = ow1[o * 256 + kc * 16 + k];
    }
    // stage X chunk: Xc[k][r] = sfeat[(row0+r)*256 + kc*16 + k]
    for (int i = tid; i < 64 * 16; i += 256) {
      int r = i >> 4, k = i & 15;
      Xc[k][r] = sfeat[(row0 + r) * 256 + kc * 16 + k];
    }
    __syncthreads();
#pragma unroll
    for (int k = 0; k < 16; ++k) {
      float4 x0 = *(const float4*)&Xc[k][rr];        // rows rr..rr+3 (broadcast)
      float4 x1 = *(const float4*)&Xc[k][rr + 4];    // rows rr+4..rr+7
      float4 w0 = *(const float4*)&Wc[k][c4];        // cols c4..c4+3
      float4 w1 = *(const float4*)&Wc[k][128 + c4];  // cols 128+c4..+3
      float x[8] = {x0.x, x0.y, x0.z, x0.w, x1.x, x1.y, x1.z, x1.w};
      float w[8] = {w0.x, w0.y, w0.z, w0.w, w1.x, w1.y, w1.z, w1.w};
#pragma unroll
      for (int r = 0; r < 8; ++r)
#pragma unroll
        for (int j = 0; j < 8; ++j)
          acc[r][j] = fmaf(x[r], w[j], acc[r][j]);
    }
  }
  __syncthreads();   // Xc/Wc dead; reuse union as Hst
#pragma unroll
  for (int j = 0; j < 8; ++j) {
    int o = (j < 4) ? (c4 + j) : (124 + c4 + j);  // j>=4: 128 + c4 + (j-4)
    float bb = ob1[o], ss = os1[o], tt = ot1[o];
#pragma unroll
    for (int r = 0; r < 8; ++r)
      Hst[o][rr + r] = fmaxf((acc[r][j] + bb) * ss + tt, 0.f);
  }
  __syncthreads();

  if (tid < 128) {
    int r = tid >> 1, o = tid & 1;
    float a = 0.f;
    for (int k = 0; k < 256; ++k)
      a = fmaf(Hst[k][r], ow2[o * 256 + k], a);
    a += ob2[o];
    int row = row0 + r;
    votes[row * 2 + o] = sxyz[row * 2 + o] + a;
  }
}

// =====================================================================
// k_fps_vf — fused fps+vf (round-7 proven structure; fps scan b128).
// =====================================================================
__global__ __launch_bounds__(512) void k_fps_vf(
    const float* __restrict__ votes, float* __restrict__ nxyz,
    float* __restrict__ out,
    const float* __restrict__ sfeat, const u16* __restrict__ FW1h,
    const float* __restrict__ fb1, const float* __restrict__ fs1,
    const float* __restrict__ ft1, const u16* __restrict__ FW2b,
    const float* __restrict__ fb2, u16* __restrict__ vfeat)
{
  __shared__ __align__(16) char smem[86016];
  const int tid = threadIdx.x;

  if (blockIdx.x < 8) {
    // ================= FPS role =================
    const int b = blockIdx.x;
    const float* vb = votes + b * Mn * 2;
    float2* xy   = (float2*)smem;                  // 65536 B
    u32*   Sd    = (u32*)(smem + 65536);           // [2][32]
    u32*   Sl    = (u32*)(smem + 65536 + 256);     // [2][32]
    float* histx = (float*)(smem + 66048);
    float* histy = (float*)(smem + 67072);

    {
      const float4* vb4 = (const float4*)vb;
#pragma unroll
      for (int j = tid; j < Mn / 2; j += 512) {
        float4 v = vb4[j];
        *(float4*)&xy[2 * j] = v;
      }
    }
    float dist[16];
#pragma unroll
    for (int s = 0; s < 16; ++s) dist[s] = 1e10f;
    __syncthreads();

    float cx = xy[0].x, cy = xy[0].y;
    if (tid == 0) { histx[0] = cx; histy[0] = cy; }

    for (int it = 1; it < Pn; ++it) {
      float bd = -1.f; int bi = 0;
#pragma unroll
      for (int s = 0; s < 8; ++s) {
        int base = s * 1024 + 2 * tid;
        float4 p2 = *(const float4*)&xy[base];   // pts base, base+1
        float dx0 = p2.x - cx, dy0 = p2.y - cy;
        float d0 = fminf(dist[2 * s], dx0 * dx0 + dy0 * dy0);
        dist[2 * s] = d0;
        if (d0 > bd) { bd = d0; bi = base; }
        float dx1 = p2.z - cx, dy1 = p2.w - cy;
        float d1 = fminf(dist[2 * s + 1], dx1 * dx1 + dy1 * dy1);
        dist[2 * s + 1] = d1;
        if (d1 > bd) { bd = d1; bi = base + 1; }
      }

      u32 hd = __float_as_uint(bd), hl = ~(u32)bi;

#define FPS_ROR(VD, VL, N)                                                      \
      {                                                                         \
        u32 od = (u32)__builtin_amdgcn_update_dpp(0, (int)VD, 0x120 + N, 0xF, 0xF, false); \
        u32 ol = (u32)__builtin_amdgcn_update_dpp(0, (int)VL, 0x120 + N, 0xF, 0xF, false); \
        bool g = (od > VD) || (od == VD && ol > VL);                            \
        VD = g ? od : VD; VL = g ? ol : VL;                                     \
      }
      FPS_ROR(hd, hl, 8)
      FPS_ROR(hd, hl, 4)
      FPS_ROR(hd, hl, 2)
      FPS_ROR(hd, hl, 1)

      const int buf = it & 1;
      if ((tid & 15) == 0) {
        int row = tid >> 4;              // 0..31
        Sd[buf * 32 + row] = hd; Sl[buf * 32 + row] = hl;
      }
      __syncthreads();

      int rr = tid & 15;
      u32 rd = Sd[buf * 32 + rr], rl = Sl[buf * 32 + rr];
      {
        u32 od = Sd[buf * 32 + 16 + rr], ol = Sl[buf * 32 + 16 + rr];
        bool g = (od > rd) || (od == rd && ol > rl);
        rd = g ? od : rd; rl = g ? ol : rl;
      }
      FPS_ROR(rd, rl, 8)
      FPS_ROR(rd, rl, 4)
      FPS_ROR(rd, rl, 2)
      FPS_ROR(rd, rl, 1)
#undef FPS_ROR

      int widx = (int)(~rl);
      float2 w = xy[widx];               // uniform addr -> LDS broadcast
      cx = w.x; cy = w.y;
      if (tid == 0) { histx[it] = cx; histy[it] = cy; }
    }
    __syncthreads();
    if (tid < 256) {
      float2 o2; o2.x = histx[tid]; o2.y = histy[tid];
      *(float2*)&nxyz[(b * Pn + tid) * 2] = o2;
      *(float2*)&out[(b * Pn + tid) * 2] = o2;
    }
  } else {
    // ================= VF role (8-wave remap, proven) =================
    const int bx = blockIdx.x - 8;
    const int row0 = bx * 128;
    u16* Hs = (u16*)smem;                  // 128*136*2 = 34816
    u16* As = (u16*)(smem + 34816);        // 128*40*2  = 10240
    u16* Bs = (u16*)(smem + 45056);        // 128*40*2  = 10240

    const int wid = tid >> 6, lane = tid & 63, m16 = lane & 15, quad = lane >> 4;
    const int wr = wid >> 2;        // 0..1 : 64-row group
    const int wc4 = wid & 3;        // 0..3 : 32-col group
    const int sr = tid >> 2, sk = (tid & 3) * 8;

    f32x4 acc2[4][2];
#pragma unroll
    for (int mt = 0; mt < 4; ++mt)
#pragma unroll
      for (int nt = 0; nt < 2; ++nt) acc2[mt][nt] = (f32x4){0.f, 0.f, 0.f, 0.f};

    for (int h = 0; h < 2; ++h) {
      f32x4 acc[4][2];
#pragma unroll
      for (int mt = 0; mt < 4; ++mt)
#pragma unroll
        for (int nt = 0; nt < 2; ++nt) acc[mt][nt] = (f32x4){0.f, 0.f, 0.f, 0.f};

      for (int s = 0; s < 8; ++s) {
        __syncthreads();
        {
          const float* src = &sfeat[(row0 + sr) * 256 + s * 32 + sk];
          float4 v0 = *(const float4*)&src[0];
          float4 v1 = *(const float4*)&src[4];
          u32 packed[4];
          packed[0] = (u32)f2bf(v0.x) | ((u32)f2bf(v0.y) << 16);
          packed[1] = (u32)f2bf(v0.z) | ((u32)f2bf(v0.w) << 16);
          packed[2] = (u32)f2bf(v1.x) | ((u32)f2bf(v1.y) << 16);
          packed[3] = (u32)f2bf(v1.z) | ((u32)f2bf(v1.w) << 16);
          *(uint4*)&As[sr * 40 + sk] = *(uint4*)&packed[0];
          *(uint4*)&Bs[sr * 40 + sk] =
              *(const uint4*)&FW1h[(h * 128 + sr) * 256 + s * 32 + sk];
        }
        __syncthreads();
#pragma unroll
        for (int mt = 0; mt < 4; ++mt) {
          bf16x8 af = *(const bf16x8*)&As[(wr * 64 + mt * 16 + m16) * 40 + quad * 8];
#pragma unroll
          for (int nt = 0; nt < 2; ++nt) {
            bf16x8 bfr = *(const bf16x8*)&Bs[(wc4 * 32 + nt * 16 + m16) * 40 + quad * 8];
            acc[mt][nt] = __builtin_amdgcn_mfma_f32_16x16x32_bf16(af, bfr, acc[mt][nt], 0, 0, 0);
          }
        }
      }
      __syncthreads();
#pragma unroll
      for (int nt = 0; nt < 2; ++nt) {
        int colL = wc4 * 32 + nt * 16 + m16;
        int col = h * 128 + colL;
        float bb = fb1[col], ss = fs1[col], tt = ft1[col];
#pragma unroll
        for (int mt = 0; mt < 4; ++mt) {
          int rL = wr * 64 + mt * 16 + quad * 4;
#pragma unroll
          for (int r = 0; r < 4; ++r)
            Hs[(rL + r) * 136 + colL] = f2bf(fmaxf((acc[mt][nt][r] + bb) * ss + tt, 0.f));
        }
      }
      for (int s2 = 0; s2 < 4; ++s2) {
        __syncthreads();
        {
          *(uint4*)&Bs[sr * 40 + sk] =
              *(const uint4*)&FW2b[sr * 256 + h * 128 + s2 * 32 + sk];
        }
        __syncthreads();
#pragma unroll
        for (int mt = 0; mt < 4; ++mt) {
          bf16x8 af = *(const bf16x8*)&Hs[(wr * 64 + mt * 16 + m16) * 136 + s2 * 32 + quad * 8];
#pragma unroll
          for (int nt = 0; nt < 2; ++nt) {
            bf16x8 bfr = *(const bf16x8*)&Bs[(wc4 * 32 + nt * 16 + m16) * 40 + quad * 8];
            acc2[mt][nt] = __builtin_amdgcn_mfma_f32_16x16x32_bf16(af, bfr, acc2[mt][nt], 0, 0, 0);
          }
        }
      }
    }
#pragma unroll
    for (int nt = 0; nt < 2; ++nt) {
      int col = wc4 * 32 + nt * 16 + m16;
      float bb = fb2[col];
#pragma unroll
      for (int mt = 0; mt < 4; ++mt) {
        int rbase = row0 + wr * 64 + mt * 16 + quad * 4;
#pragma unroll
        for (int r = 0; r < 4; ++r)
          vfeat[(rbase + r) * 128 + col] = f2bf(acc2[mt][nt][r] + bb);
      }
    }
  }
}

// =====================================================================
// Ball query — standalone again (round-9 fusion regressed: ballq is
// latency-bound and needs high occupancy; agg's 54KB LDS starved it).
// =====================================================================
__global__ __launch_bounds__(256) void k_ballq(
    const float* __restrict__ votes, const float* __restrict__ nxyz,
    int* __restrict__ gidx)
{
  const int bp = blockIdx.x, tid = threadIdx.x;
  const int b = bp >> 8;
  const float* vb = votes + b * Mn * 2;
  const float sx = nxyz[bp * 2], sy = nxyz[bp * 2 + 1];
  const float a = sx * sx + sy * sy;
  float d2[32];
#pragma unroll
  for (int s = 0; s < 32; ++s) {
    int i = tid * 32 + s;
    float x = vb[i * 2], y = vb[i * 2 + 1];
    d2[s] = (a + (x * x + y * y)) - 2.f * (sx * x + sy * y);
  }
  __shared__ float sd[4];
  __shared__ int si[4];
  __shared__ int swi;
  unsigned mask = 0;
  for (int kk = 0; kk < Kn; ++kk) {
    float bd = 3.4e38f; int bi = 0x7fffffff;
#pragma unroll
    for (int s = 0; s < 32; ++s)
      if (!((mask >> s) & 1u) && d2[s] < bd) { bd = d2[s]; bi = tid * 32 + s; }
#pragma unroll
    for (int off = 32; off > 0; off >>= 1) {
      float od = __shfl_xor(bd, off);
      int oi = __shfl_xor(bi, off);
      if (od < bd || (od == bd && oi < bi)) { bd = od; bi = oi; }
    }
    if ((tid & 63) == 0) { sd[tid >> 6] = bd; si[tid >> 6] = bi; }
    __syncthreads();
    if (tid == 0) {
#pragma unroll
      for (int w = 1; w < 4; ++w)
        if (sd[w] < bd || (sd[w] == bd && si[w] < bi)) { bd = sd[w]; bi = si[w]; }
      swi = bi;
      gidx[bp * Kn + kk] = (bd > R2) ? 0 : bi;
    }
    __syncthreads();
    int wi = swi;
    if ((wi >> 5) == tid) mask |= 1u << (wi & 31);
  }
}

// =====================================================================
// Prep: bf16 weight conversions. No deps -> launched first.
// =====================================================================
__global__ __launch_bounds__(256) void k_prep(
    const float* __restrict__ fw1, const float* __restrict__ fw2,
    const float* __restrict__ aw1, const float* __restrict__ aw2,
    u16* __restrict__ FW1h, u16* __restrict__ FW2b,
    u16* __restrict__ AW1b, u16* __restrict__ AW2b)
{
  const int gid = blockIdx.x * 256 + threadIdx.x;
  const int gsz = gridDim.x * 256;
  for (int i = gid; i < 65536; i += gsz) FW1h[i] = f2bf(fw1[i]);
  for (int i = gid; i < 32768; i += gsz) FW2b[i] = f2bf(fw2[i]);
  for (int i = gid; i < 65536; i += gsz) AW2b[i] = f2bf(aw2[i]);
  for (int i = gid; i < 49152; i += gsz) {
    int o = i / 192, k = i % 192;
    AW1b[i] = (k < 130) ? f2bf(aw1[o * 130 + k]) : (u16)0;
  }
}

// =====================================================================
// k_agg_head — round-8 verbatim (proven).
// =====================================================================
__global__ __launch_bounds__(256) void k_agg_head(
    const float* __restrict__ votes, const u16* __restrict__ vfeat,
    const float* __restrict__ nxyz, const int* __restrict__ gidx,
    const u16* __restrict__ AW1b, const float* __restrict__ ab1,
    const float* __restrict__ as1, const float* __restrict__ at1,
    const u16* __restrict__ AW2b, const float* __restrict__ ab2,
    const float* __restrict__ as2, const float* __restrict__ at2,
    const float* __restrict__ pw1, const float* __restrict__ pb1,
    const float* __restrict__ ps1, const float* __restrict__ pt1,
    const float* __restrict__ pw2, const float* __restrict__ pb2,
    const float* __restrict__ ps2, const float* __restrict__ pt2,
    const float* __restrict__ objw, const float* __restrict__ objb,
    const float* __restrict__ clsw, const float* __restrict__ clsb,
    float* __restrict__ out)
{
  __shared__ u16 U[32 * 264];
  __shared__ u16 Bs[256 * 72];
  __shared__ int gix[32];
  __shared__ float gvx[32], gvy[32];
  u16* CombA = U;
  u16* As = U;
  float* x2T = (float*)Bs;
  float* xr = (float*)U;          // head buffers aliased on dead U
  float* y1 = ((float*)U) + 256;
  float* y2 = ((float*)U) + 512;

  const int bp = blockIdx.x, tid = threadIdx.x, b = bp >> 8;
  if (tid < 32) {
    int g = gidx[bp * 32 + tid];
    gix[tid] = g;
    gvx[tid] = votes[(b * Mn + g) * 2];
    gvy[tid] = votes[(b * Mn + g) * 2 + 1];
  }
  __syncthreads();
  const float sx = nxyz[bp * 2], sy = nxyz[bp * 2 + 1];

  if (tid < 192) {
    int row = tid / 6, c = tid % 6;
    const u16* vsrc = &vfeat[(b * Mn + gix[row]) * 128];
    u16* dst = &CombA[row * 200 + c * 32];
    if (c == 0) {
      dst[0] = f2bf(gvx[row] - sx);
      dst[1] = f2bf(gvy[row] - sy);
      for (int k = 2; k < 32; ++k) dst[k] = vsrc[k - 2];
    } else if (c <= 3) {
      for (int k = 0; k < 32; ++k) dst[k] = vsrc[c * 32 + k - 2];
    } else if (c == 4) {
      dst[0] = vsrc[126]; dst[1] = vsrc[127];
      for (int k = 2; k < 32; ++k) dst[k] = 0;
    } else {
      for (int k = 0; k < 32; ++k) dst[k] = 0;
    }
  }

  const int wid = tid >> 6, lane = tid & 63, m16 = lane & 15, quad = lane >> 4;
  const int mt = wid & 1, nh = wid >> 1;

  f32x4 acc[8];
#pragma unroll
  for (int nt = 0; nt < 8; ++nt) acc[nt] = (f32x4){0.f, 0.f, 0.f, 0.f};
  for (int s = 0; s < 3; ++s) {
    __syncthreads();
    for (int i = tid; i < 4096; i += 256) {
      int n = i >> 4, c4 = i & 15;
      *(uint2*)&Bs[n * 72 + c4 * 4] = *(const uint2*)&AW1b[n * 192 + s * 64 + c4 * 4];
    }
    __syncthreads();
#pragma unroll
    for (int ks = 0; ks < 2; ++ks) {
      bf16x8 af = *(const bf16x8*)&CombA[(mt * 16 + m16) * 200 + s * 64 + ks * 32 + quad * 8];
#pragma unroll
      for (int nt = 0; nt < 8; ++nt) {
        bf16x8 bf_ = *(const bf16x8*)&Bs[(nh * 128 + nt * 16 + m16) * 72 + ks * 32 + quad * 8];
        acc[nt] = __builtin_amdgcn_mfma_f32_16x16x32_bf16(af, bf_, acc[nt], 0, 0, 0);
      }
    }
  }
  __syncthreads();
#pragma unroll
  for (int nt = 0; nt < 8; ++nt) {
    int col = nh * 128 + nt * 16 + m16;
    float bb = ab1[col], ss = as1[col], tt = at1[col];
#pragma unroll
    for (int r = 0; r < 4; ++r) {
      int samp = mt * 16 + quad * 4 + r;
      As[samp * 264 + col] = f2bf(fmaxf((acc[nt][r] + bb) * ss + tt, 0.f));
    }
  }

  f32x4 acc2[8];
#pragma unroll
  for (int nt = 0; nt < 8; ++nt) acc2[nt] = (f32x4){0.f, 0.f, 0.f, 0.f};
  for (int s = 0; s < 4; ++s) {
    __syncthreads();
    for (int i = tid; i < 4096; i += 256) {
      int n = i >> 4, c4 = i & 15;
      *(uint2*)&Bs[n * 72 + c4 * 4] = *(const uint2*)&AW2b[n * 256 + s * 64 + c4 * 4];
    }
    __syncthreads();
#pragma unroll
    for (int ks = 0; ks < 2; ++ks) {
      bf16x8 af = *(const bf16x8*)&As[(mt * 16 + m16) * 264 + s * 64 + ks * 32 + quad * 8];
#pragma unroll
      for (int nt = 0; nt < 8; ++nt) {
        bf16x8 bf_ = *(const bf16x8*)&Bs[(nh * 128 + nt * 16 + m16) * 72 + ks * 32 + quad * 8];
        acc2[nt] = __builtin_amdgcn_mfma_f32_16x16x32_bf16(af, bf_, acc2[nt], 0, 0, 0);
      }
    }
  }
  __syncthreads();
#pragma unroll
  for (int nt = 0; nt < 8; ++nt) {
    int col = nh * 128 + nt * 16 + m16;
    float bb = ab2[col], ss = as2[col], tt = at2[col];
#pragma unroll
    for (int r = 0; r < 4; ++r) {
      int samp = mt * 16 + quad * 4 + r;
      x2T[col * 33 + samp] = fmaxf((acc2[nt][r] + bb) * ss + tt, 0.f);
    }
  }
  __syncthreads();     // As (U) reads done before this; U now dead
  {
    float m = x2T[tid * 33];
#pragma unroll
    for (int s2 = 1; s2 < 32; ++s2) m = fmaxf(m, x2T[tid * 33 + s2]);
    xr[tid] = m;       // == pooled[bp*256+tid], bit-exact
  }
  __syncthreads();

  // ---- head (identical arithmetic to proven k_head) ----
  {
    float a = 0.f;
    for (int c = 0; c < 256; ++c) a = fmaf(xr[c], pw1[tid * 256 + c], a);
    a = (a + pb1[tid]) * ps1[tid] + pt1[tid];
    y1[tid] = fmaxf(a, 0.f);
  }
  __syncthreads();
  if (tid < 128) {
    float a = 0.f;
    for (int c = 0; c < 256; ++c) a = fmaf(y1[c], pw2[tid * 256 + c], a);
    a = (a + pb2[tid]) * ps2[tid] + pt2[tid];
    y2[tid] = fmaxf(a, 0.f);
  }
  __syncthreads();
  if (tid < 10) {
    float a = 0.f;
    for (int c = 0; c < 128; ++c) a = fmaf(y2[c], clsw[tid * 128 + c], a);
    out[6144 + bp * 10 + tid] = a + clsb[tid];
  } else if (tid == 10) {
    float a = 0.f;
    for (int c = 0; c < 128; ++c) a = fmaf(y2[c], objw[c], a);
    out[4096 + bp] = a + objb[0];
  }
}

// =====================================================================
extern "C" void kernel_launch(void* const* d_in, const int* in_sizes, int n_in,
                              void* d_out, int out_size, void* d_ws, size_t ws_size,
                              hipStream_t stream)
{
  (void)in_sizes; (void)n_in; (void)out_size; (void)ws_size;
  const float* sxyz  = (const float*)d_in[0];
  const float* sfeat = (const float*)d_in[1];
  const float* ow1 = (const float*)d_in[2];
  const float* ob1 = (const float*)d_in[3];
  const float* os1 = (const float*)d_in[4];
  const float* ot1 = (const float*)d_in[5];
  const float* ow2 = (const float*)d_in[6];
  const float* ob2 = (const float*)d_in[7];
  const float* fw1 = (const float*)d_in[8];
  const float* fb1 = (const float*)d_in[9];
  const float* fs1 = (const float*)d_in[10];
  const float* ft1 = (const float*)d_in[11];
  const float* fw2 = (const float*)d_in[12];
  const float* fb2 = (const float*)d_in[13];
  const float* aw1 = (const float*)d_in[14];
  const float* ab1 = (const float*)d_in[15];
  const float* as1 = (const float*)d_in[16];
  const float* at1 = (const float*)d_in[17];
  const float* aw2 = (const float*)d_in[18];
  const float* ab2 = (const float*)d_in[19];
  const float* as2 = (const float*)d_in[20];
  const float* at2 = (const float*)d_in[21];
  const float* pw1 = (const float*)d_in[22];
  const float* pb1 = (const float*)d_in[23];
  const float* ps1 = (const float*)d_in[24];
  const float* pt1 = (const float*)d_in[25];
  const float* pw2 = (const float*)d_in[26];
  const float* pb2 = (const float*)d_in[27];
  const float* ps2 = (const float*)d_in[28];
  const float* pt2 = (const float*)d_in[29];
  const float* objw = (const float*)d_in[30];
  const float* objb = (const float*)d_in[31];
  const float* clsw = (const float*)d_in[32];
  const float* clsb = (const float*)d_in[33];

  char* ws = (char*)d_ws;
  float* votes  = (float*)(ws + 0);             //    524,288
  u16*   vfeat  = (u16*)  (ws + 524288);        // 16,777,216
  float* nxyz   = (float*)(ws + 17301504);      //     16,384
  int*   gidxp  = (int*)  (ws + 17317888);      //    262,144
  u16*   FW1h   = (u16*)  (ws + 19677184);      //    131,072
  u16*   FW2b   = (u16*)  (ws + 19808256);      //     65,536
  u16*   AW1b   = (u16*)  (ws + 19873792);      //     98,304
  u16*   AW2b   = (u16*)  (ws + 19972096);      //    131,072
  float* out    = (float*)d_out;

  // prep first (no deps) so vf-role blocks of the fused kernel are ready
  k_prep<<<dim3(256), dim3(256), 0, stream>>>(
      fw1, fw2, aw1, aw2, FW1h, FW2b, AW1b, AW2b);

  k_voting_off<<<dim3(1024), dim3(256), 0, stream>>>(
      sxyz, sfeat, ow1, ob1, os1, ot1, ow2, ob2, votes);

  // fused: blocks 0..7 = FPS (one per batch), blocks 8..519 = VF
  k_fps_vf<<<dim3(520), dim3(512), 0, stream>>>(
      votes, nxyz, out,
      sfeat, FW1h, fb1, fs1, ft1, FW2b, fb2, vfeat);

  k_ballq<<<dim3(2048), dim3(256), 0, stream>>>(votes, nxyz, gidxp);

  k_agg_head<<<dim3(2048), dim3(256), 0, stream>>>(
      votes, vfeat, nxyz, gidxp, AW1b, ab1, as1, at1,
      AW2b, ab2, as2, at2,
      pw1, pb1, ps1, pt1, pw2, pb2, ps2, pt2,
      objw, objb, clsw, clsb, out);
}